// Round 1
// baseline (905.521 us; speedup 1.0000x reference)
//
#include <hip/hip_runtime.h>
#include <stdint.h>

// ---------------------------------------------------------------------------
// SelfConnectionIntro: out[z,w,k] = alpha_l * sum_{u,v} x_l[z,u,k]*o[z,v]*W_l[u,v,w]
// Formulated per path as GEMM: C[(z,k), w] = A[(z,k), u*16+v] * B[u*16+v, w]
//   A built on the fly (x * operand outer product), B = W transposed to [w][K] bf16.
// ---------------------------------------------------------------------------

typedef __attribute__((ext_vector_type(8))) short bf16x8;   // 8 bf16 = 4 VGPR (guide §3)
typedef __attribute__((ext_vector_type(4))) float f32x4;

__device__ __forceinline__ unsigned short f2bf(float f) {
    unsigned int u = __float_as_uint(f);
    u += 0x7fffu + ((u >> 16) & 1u);          // round-to-nearest-even
    return (unsigned short)(u >> 16);
}
__device__ __forceinline__ unsigned int pack2(float a, float b) {
    return (unsigned int)f2bf(a) | ((unsigned int)f2bf(b) << 16);
}

// --- prep: Wt_l[w*K + (u*16+v)] = bf16( W_l[(u*16+v)*WM + w] ) ----------------
__global__ void prep_wt(const float* __restrict__ w0, const float* __restrict__ w1,
                        const float* __restrict__ w2, unsigned short* __restrict__ wt) {
    int i = blockIdx.x * 256 + threadIdx.x;
    if (i < 262144) {                               // path0: K=2048, WM=128
        int kk = i & 2047;
        int w  = i >> 11;
        wt[i] = f2bf(w0[kk * 128 + w]);
    } else if (i < 327680) {                        // path1: K=1024, WM=64
        int r = i - 262144;
        int kk = r & 1023, w = r >> 10;
        wt[i] = f2bf(w1[kk * 64 + w]);
    } else if (i < 344064) {                        // path2: K=512, WM=32
        int r = i - 327680;
        int kk = r & 511, w = r >> 9;
        wt[i] = f2bf(w2[kk * 32 + w]);
    }
}

// --- main GEMM per path ------------------------------------------------------
// D = 2l+1, OFF = slice offset (same for in/out), K = U*16, BN = N = mul_out.
template<int D, int OFF, int K, int BN, int BM, int WAVES_M, int WAVES_N>
__global__ __launch_bounds__(256, 2)
void fctp_gemm(const float* __restrict__ x, const float* __restrict__ op,
               const unsigned short* __restrict__ wt, float* __restrict__ out,
               int Z, float alpha)
{
    constexpr int BK   = 32;                 // 2 u-values * 16 v per step
    constexpr int LDA  = BK + 8;             // 40 shorts = 80B row stride (conflict pad)
    constexpr int NSTEP = K / BK;
    constexpr int WTM  = BM / WAVES_M;
    constexpr int WTN  = BN / WAVES_N;
    constexpr int TM   = WTM / 16;
    constexpr int TN   = WTN / 16;

    __shared__ unsigned short Asm_[BM * LDA];
    __shared__ unsigned short Bsm_[BN * LDA];

    const int tid = threadIdx.x;
    const int M   = Z * D;
    const long m0 = (long)blockIdx.x * BM;

    // A-build ownership: BM==128 -> 2 threads/row (one u each); BM==256 -> 1 thread/row
    int arow, usel;
    if constexpr (BM == 128) { arow = tid & 127; usel = tid >> 7; }
    else                     { arow = tid;       usel = 0;        }

    long mr = m0 + arow;
    if (mr >= M) mr = M - 1;                 // clamp (stores are guarded)
    const int zr = (int)(mr / D);
    const int kr = (int)(mr % D);

    // operand row lives in registers for the whole K loop
    float oreg[16];
    #pragma unroll
    for (int v = 0; v < 16; ++v) oreg[v] = op[(size_t)zr * 16 + v];

    // x pointer: x[z, OFF + u*D + k], u = 2*s + usel, advances 2*D floats/step
    const float* xp = x + (size_t)zr * 480 + OFF + kr + usel * D;

    f32x4 acc[TM][TN];
    #pragma unroll
    for (int i = 0; i < TM; ++i)
        #pragma unroll
        for (int j = 0; j < TN; ++j) acc[i][j] = f32x4{0.f, 0.f, 0.f, 0.f};

    const int lane = tid & 63;
    const int wv   = tid >> 6;
    const int wm0  = (wv / WAVES_N) * WTM;
    const int wn0  = (wv % WAVES_N) * WTN;
    const int q    = lane >> 4;              // quad
    const int l16  = lane & 15;

    for (int s = 0; s < NSTEP; ++s) {
        const int k0 = s * BK;
        __syncthreads();                     // previous compute done before overwrite

        // ---- stage B: Bt tile [BN][BK] from Wt (L2-resident) ----
        constexpr int BTOT = BN * 4;         // 16B chunks
        #pragma unroll
        for (int it = 0; it < (BTOT + 255) / 256; ++it) {
            int idx = it * 256 + tid;
            if ((BTOT % 256 == 0) || (idx < BTOT)) {
                int n = idx >> 2, qq = idx & 3;
                *(uint4*)(&Bsm_[n * LDA + qq * 8]) =
                    *(const uint4*)(wt + (size_t)n * K + k0 + qq * 8);
            }
        }

        // ---- stage A: products x*o -> bf16 -> LDS ----
        if constexpr (BM == 128) {
            float xv = *xp; xp += 2 * D;
            unsigned int pk[8];
            #pragma unroll
            for (int vv = 0; vv < 8; ++vv)
                pk[vv] = pack2(xv * oreg[2 * vv], xv * oreg[2 * vv + 1]);
            uint4* dst = (uint4*)(&Asm_[arow * LDA + usel * 16]);
            dst[0] = uint4{pk[0], pk[1], pk[2], pk[3]};
            dst[1] = uint4{pk[4], pk[5], pk[6], pk[7]};
        } else {
            float xv0 = xp[0], xv1 = xp[D]; xp += 2 * D;
            unsigned int pk[16];
            #pragma unroll
            for (int vv = 0; vv < 8; ++vv) {
                pk[vv]     = pack2(xv0 * oreg[2 * vv], xv0 * oreg[2 * vv + 1]);
                pk[8 + vv] = pack2(xv1 * oreg[2 * vv], xv1 * oreg[2 * vv + 1]);
            }
            uint4* dst = (uint4*)(&Asm_[arow * LDA]);
            dst[0] = uint4{pk[0],  pk[1],  pk[2],  pk[3]};
            dst[1] = uint4{pk[4],  pk[5],  pk[6],  pk[7]};
            dst[2] = uint4{pk[8],  pk[9],  pk[10], pk[11]};
            dst[3] = uint4{pk[12], pk[13], pk[14], pk[15]};
        }
        __syncthreads();

        // ---- fragments + MFMA ----
        bf16x8 af[TM], bfr[TN];
        #pragma unroll
        for (int i = 0; i < TM; ++i)
            af[i] = *(const bf16x8*)(&Asm_[(wm0 + i * 16 + l16) * LDA + q * 8]);
        #pragma unroll
        for (int j = 0; j < TN; ++j)
            bfr[j] = *(const bf16x8*)(&Bsm_[(wn0 + j * 16 + l16) * LDA + q * 8]);
        #pragma unroll
        for (int i = 0; i < TM; ++i)
            #pragma unroll
            for (int j = 0; j < TN; ++j)
                acc[i][j] = __builtin_amdgcn_mfma_f32_16x16x32_bf16(
                    af[i], bfr[j], acc[i][j], 0, 0, 0);
    }

    // ---- epilogue: C/D layout col=lane&15, row=quad*4+reg (m89-verified) ----
    #pragma unroll
    for (int i = 0; i < TM; ++i) {
        #pragma unroll
        for (int p = 0; p < 4; ++p) {
            long m = m0 + wm0 + i * 16 + q * 4 + p;
            if (m < M) {
                int z = (int)(m / D);
                int k = (int)(m % D);
                float* orow = out + (size_t)z * 480 + OFF + k;
                #pragma unroll
                for (int j = 0; j < TN; ++j) {
                    int col = wn0 + j * 16 + l16;
                    orow[col * D] = alpha * acc[i][j][p];
                }
            }
        }
    }
}

extern "C" void kernel_launch(void* const* d_in, const int* in_sizes, int n_in,
                              void* d_out, int out_size, void* d_ws, size_t ws_size,
                              hipStream_t stream) {
    (void)n_in; (void)out_size; (void)ws_size;
    const float* x  = (const float*)d_in[0];
    const float* op = (const float*)d_in[1];
    const float* w0 = (const float*)d_in[2];
    const float* w1 = (const float*)d_in[3];
    const float* w2 = (const float*)d_in[4];
    float* out = (float*)d_out;
    const int Z = in_sizes[0] / 480;

    unsigned short* wt = (unsigned short*)d_ws;    // 344064 bf16 = 688128 B
    prep_wt<<<1344, 256, 0, stream>>>(w0, w1, w2, wt);

    const unsigned short* wt0 = wt;
    const unsigned short* wt1 = wt + 262144;
    const unsigned short* wt2 = wt + 327680;

    // path0: 128x0e, D=1, K=2048, N=128;  alpha = 1/sqrt(128*16)
    {
        int M = Z, BM = 128;
        fctp_gemm<1, 0, 2048, 128, 128, 2, 2>
            <<<(M + BM - 1) / BM, 256, 0, stream>>>(x, op, wt0, out, Z, 0.02209708691f);
    }
    // path1: 64x1o, D=3, K=1024, N=64;  alpha = 1/sqrt(64*16)
    {
        int M = Z * 3, BM = 256;
        fctp_gemm<3, 128, 1024, 64, 256, 2, 2>
            <<<(M + BM - 1) / BM, 256, 0, stream>>>(x, op, wt1, out, Z, 0.03125f);
    }
    // path2: 32x2e, D=5, K=512, N=32;  alpha = 1/sqrt(32*16)
    {
        int M = Z * 5, BM = 256;
        fctp_gemm<5, 320, 512, 32, 256, 4, 1>
            <<<(M + BM - 1) / BM, 256, 0, stream>>>(x, op, wt2, out, Z, 0.04419417382f);
    }
}